// Round 1
// baseline (418.219 us; speedup 1.0000x reference)
//
#include <hip/hip_runtime.h>

#define BB 4
#define TT 32
#define DD 256
#define NN 1024

// ws layout (float indices)
#define XN_OFF 0                    // xn_buf [B*T][N]
#define TN_OFF (BB*TT*NN)           // tn_buf [B*T][N]  (tn_buf[b][t] = tgt_neurons[b][t+1])
#define PB_OFF (2*BB*TT*NN)         // p_buf  [(b*T+t)*2 + phase][N]
#define YW_OFF (PB_OFF + 2*BB*TT*NN)// y_ws   [B*T][D]
#define CNT_OFF (YW_OFF + BB*TT*DD) // cnt    [B*T*2] uints

// ---------------- kernel 1: xn = relu(LN(x @ E)), tn shifted ----------------
__global__ __launch_bounds__(256) void precompute_kernel(
    const float* __restrict__ x_seq, const float* __restrict__ targets,
    const float* __restrict__ E, float* __restrict__ ws)
{
    __shared__ float xrow[DD];
    __shared__ float red[8];
    const int task = blockIdx.x;       // 0..255
    const int is_t = task >> 7;        // 0: x_seq, 1: targets
    const int bt   = task & 127;       // b*32 + t
    const int t    = bt & 31;
    const int tid  = threadIdx.x;

    const float* src = (is_t ? targets : x_seq) + bt * DD;
    xrow[tid] = src[tid];
    __syncthreads();

    const float4* E4 = (const float4*)E;
    float a0 = 0.f, a1 = 0.f, a2 = 0.f, a3 = 0.f;
#pragma unroll 8
    for (int k = 0; k < DD; ++k) {
        float xv = xrow[k];
        float4 e = E4[k * (NN / 4) + tid];
        a0 += xv * e.x; a1 += xv * e.y; a2 += xv * e.z; a3 += xv * e.w;
    }
    float s  = a0 + a1 + a2 + a3;
    float ss = a0*a0 + a1*a1 + a2*a2 + a3*a3;
#pragma unroll
    for (int d = 1; d < 64; d <<= 1) {
        s  += __shfl_xor(s, d, 64);
        ss += __shfl_xor(ss, d, 64);
    }
    const int lane = tid & 63, w = tid >> 6;
    if (lane == 0) { red[w*2] = s; red[w*2+1] = ss; }
    __syncthreads();
    s  = red[0] + red[2] + red[4] + red[6];
    ss = red[1] + red[3] + red[5] + red[7];
    const float mu  = s * (1.0f / NN);
    const float var = ss * (1.0f / NN) - mu * mu;
    const float inv = rsqrtf(var + 1e-5f);

    float4 o;
    o.x = fmaxf(0.f, (a0 - mu) * inv);
    o.y = fmaxf(0.f, (a1 - mu) * inv);
    o.z = fmaxf(0.f, (a2 - mu) * inv);
    o.w = fmaxf(0.f, (a3 - mu) * inv);

    float* dst = nullptr;
    if (!is_t)      dst = ws + XN_OFF + (size_t)bt * NN;       // xn[b][t]
    else if (t > 0) dst = ws + TN_OFF + (size_t)(bt - 1) * NN; // tn_next[b][t-1] = tgt_neurons[b][t]
    if (dst) ((float4*)dst)[tid] = o;
    // tn_next[b][T-1] is never read (no update at last step)
}

// ---------------- kernel 2: persistent per-batch chain ----------------
__device__ __forceinline__ void wait_count(unsigned* c, unsigned target) {
    int guard = 0;
    while (__hip_atomic_load(c, __ATOMIC_ACQUIRE, __HIP_MEMORY_SCOPE_AGENT) < target) {
        __builtin_amdgcn_s_sleep(1);
        if (++guard > (1 << 25)) break;  // bailout: avoid hard hang
    }
}

__global__ __launch_bounds__(512, 2) void chain_kernel(
    const float* __restrict__ Dy, float* __restrict__ ws)
{
    __shared__ float x_lds[NN];
    __shared__ float p_lds[NN];
    __shared__ float r_lds[64];
    __shared__ float tn_lds[64];

    const int blk  = blockIdx.x;     // 64 blocks
    const int b    = blk >> 4;       // batch
    const int wg   = blk & 15;       // 16 WGs per batch
    const int base = wg * 64;        // first owned column
    const int tid  = threadIdx.x;
    const int lane = tid & 63;
    const int w    = tid >> 6;       // wave 0..7
    const int colw = base + 8 * w;   // this wave's first column

    const float* xn = ws + XN_OFF + (size_t)b * TT * NN;
    const float* tn = ws + TN_OFF + (size_t)b * TT * NN;
    float* pb       = ws + PB_OFF;
    float* yw       = ws + YW_OFF;
    unsigned* cnt   = (unsigned*)(ws + CNT_OFF);

    // G columns in registers: rows 16*lane + i, cols colw + c
    float G[16][8];
#pragma unroll
    for (int i = 0; i < 16; ++i)
#pragma unroll
        for (int c = 0; c < 8; ++c)
            G[i][c] = (16 * lane + i == colw + c) ? 0.01f : 0.0f;

    // matvec over LDS vector: returns this lane's column value (lane&7 selects col)
    auto matvec = [&](const float* v_lds) -> float {
        float acc[8] = {0,0,0,0,0,0,0,0};
        const float4* v4 = (const float4*)v_lds;
#pragma unroll
        for (int ii = 0; ii < 4; ++ii) {
            float4 xv = v4[lane * 4 + ii];
            const int i0 = 4 * ii;
#pragma unroll
            for (int c = 0; c < 8; ++c) {
                acc[c] += xv.x * G[i0 + 0][c];
                acc[c] += xv.y * G[i0 + 1][c];
                acc[c] += xv.z * G[i0 + 2][c];
                acc[c] += xv.w * G[i0 + 3][c];
            }
        }
#pragma unroll
        for (int d = 1; d < 64; d <<= 1)
#pragma unroll
            for (int c = 0; c < 8; ++c) acc[c] += __shfl_xor(acc[c], d, 64);
        float val = acc[0];
#pragma unroll
        for (int c = 1; c < 8; ++c) if ((lane & 7) == c) val = acc[c];
        return val;
    };

    for (int t = 0; t < TT; ++t) {
        const int bt = b * TT + t;
        __syncthreads();  // protect x_lds vs previous iteration's update reads
        x_lds[tid]       = xn[(size_t)t * NN + tid];
        x_lds[tid + 512] = xn[(size_t)t * NN + tid + 512];
        __syncthreads();

        // ---- phase A: p1 = xn^T G ----
        float v1 = matvec(x_lds);
        if (lane < 8)
            __hip_atomic_store(&pb[(size_t)(bt * 2 + 0) * NN + colw + lane], v1,
                               __ATOMIC_RELAXED, __HIP_MEMORY_SCOPE_AGENT);
        __syncthreads();
        if (tid == 0)
            __hip_atomic_fetch_add(&cnt[bt * 2 + 0], 1u, __ATOMIC_RELEASE, __HIP_MEMORY_SCOPE_AGENT);

        // ---- phase B: p2 = p1^T G ----
        if (tid == 0) wait_count(&cnt[bt * 2 + 0], 16u);
        __syncthreads();
        p_lds[tid]       = __hip_atomic_load(&pb[(size_t)(bt * 2 + 0) * NN + tid],
                                             __ATOMIC_RELAXED, __HIP_MEMORY_SCOPE_AGENT);
        p_lds[tid + 512] = __hip_atomic_load(&pb[(size_t)(bt * 2 + 0) * NN + tid + 512],
                                             __ATOMIC_RELAXED, __HIP_MEMORY_SCOPE_AGENT);
        __syncthreads();
        float v2 = matvec(p_lds);
        if (lane < 8)
            __hip_atomic_store(&pb[(size_t)(bt * 2 + 1) * NN + colw + lane], v2,
                               __ATOMIC_RELAXED, __HIP_MEMORY_SCOPE_AGENT);
        __syncthreads();
        if (tid == 0)
            __hip_atomic_fetch_add(&cnt[bt * 2 + 1], 1u, __ATOMIC_RELEASE, __HIP_MEMORY_SCOPE_AGENT);

        // ---- phase C: p3 = p2^T G (consumed locally) ----
        if (tid == 0) wait_count(&cnt[bt * 2 + 1], 16u);
        __syncthreads();
        p_lds[tid]       = __hip_atomic_load(&pb[(size_t)(bt * 2 + 1) * NN + tid],
                                             __ATOMIC_RELAXED, __HIP_MEMORY_SCOPE_AGENT);
        p_lds[tid + 512] = __hip_atomic_load(&pb[(size_t)(bt * 2 + 1) * NN + tid + 512],
                                             __ATOMIC_RELAXED, __HIP_MEMORY_SCOPE_AGENT);
        __syncthreads();
        float v3 = matvec(p_lds);

        float r = fmaxf(v1, fmaxf(v2, v3));
        if (lane < 8) r_lds[8 * w + lane] = r;
        __syncthreads();

        // ---- y partial: y[d] += sum over owned cols reasoning[col]*Dy[col][d] ----
        {
            const int d = tid & 255;
            const int h = tid >> 8;  // 0/1: halves of the 64 owned columns
            float acc = 0.f;
#pragma unroll
            for (int j = 0; j < 32; ++j) {
                const int cl = h * 32 + j;
                acc += r_lds[cl] * Dy[(size_t)(base + cl) * DD + d];
            }
            atomicAdd(&yw[(size_t)bt * DD + d], acc);
        }

        // ---- G update: G = max(G, 0.5*xn*tn_next^T), skip last step ----
        if (t < TT - 1) {
            if (tid < 64) tn_lds[tid] = tn[(size_t)t * NN + base + tid];
            __syncthreads();
#pragma unroll
            for (int c = 0; c < 8; ++c) {
                const float tc = 0.5f * tn_lds[8 * w + c];
#pragma unroll
                for (int i = 0; i < 16; ++i)
                    G[i][c] = fmaxf(G[i][c], x_lds[16 * lane + i] * tc);
            }
        }
    }
}

// ---------------- kernel 3: final relu ----------------
__global__ __launch_bounds__(256) void relu_out_kernel(
    const float* __restrict__ yw, float* __restrict__ out, int n)
{
    int i = blockIdx.x * blockDim.x + threadIdx.x;
    if (i < n) out[i] = fmaxf(yw[i], 0.0f);
}

extern "C" void kernel_launch(void* const* d_in, const int* in_sizes, int n_in,
                              void* d_out, int out_size, void* d_ws, size_t ws_size,
                              hipStream_t stream) {
    const float* x_seq   = (const float*)d_in[0];
    const float* targets = (const float*)d_in[1];
    const float* E       = (const float*)d_in[2];
    const float* Dy      = (const float*)d_in[3];
    float* out = (float*)d_out;
    float* ws  = (float*)d_ws;

    // zero y accumulator + sync counters (contiguous region)
    hipMemsetAsync(ws + YW_OFF, 0, (size_t)(BB * TT * DD + BB * TT * 2) * sizeof(float), stream);

    precompute_kernel<<<2 * BB * TT, 256, 0, stream>>>(x_seq, targets, E, ws);
    chain_kernel<<<BB * 16, 512, 0, stream>>>(Dy, ws);
    relu_out_kernel<<<(BB * TT * DD + 255) / 256, 256, 0, stream>>>(ws + YW_OFF, out, BB * TT * DD);
}

// Round 3
// 337.376 us; speedup vs baseline: 1.2396x; 1.2396x over previous
//
#include <hip/hip_runtime.h>

#define BB 4
#define TT 32
#define DD 256
#define NN 1024

// ws layout (float indices)
#define XN_OFF 0                      // xn_buf [B*T][N]
#define TN_OFF (BB*TT*NN)             // tn_buf [B*T][N]  (tn_buf[b][t] = tgt_neurons[b][t+1])
#define PB_OFF (2*BB*TT*NN)           // pb64  [(b*T+t)*2 + phase][N] of u64 (value<<32 | seq)
#define YW_OFF (PB_OFF + 4*BB*TT*NN)  // y_ws  [B*T][D]

// ------------- kernel 1: xn = relu(LN(x @ E)), tn shifted; 4 rows/block -------------
// One block handles bt0=2*blk and bt1=2*blk+1 for BOTH x_seq and targets (4 LN rows),
// sharing the E reads. Grid must be BB*TT/2 = 64 blocks.
__global__ __launch_bounds__(256) void precompute_kernel(
    const float* __restrict__ x_seq, const float* __restrict__ targets,
    const float* __restrict__ E, float* __restrict__ ws)
{
    __shared__ float xr[4][DD];
    __shared__ float redS[4][4], redSS[4][4];
    const int blk = blockIdx.x;        // 0..63
    const int bt0 = blk * 2;
    const int bt1 = bt0 + 1;
    const int tid = threadIdx.x;       // 0..255
    const int lane = tid & 63, w = tid >> 6;

    xr[0][tid] = x_seq[(size_t)bt0 * DD + tid];
    xr[1][tid] = x_seq[(size_t)bt1 * DD + tid];
    xr[2][tid] = targets[(size_t)bt0 * DD + tid];
    xr[3][tid] = targets[(size_t)bt1 * DD + tid];
    __syncthreads();

    const float4* E4 = (const float4*)E;
    float4 acc[4];
#pragma unroll
    for (int r = 0; r < 4; ++r) acc[r] = make_float4(0.f, 0.f, 0.f, 0.f);
#pragma unroll 4
    for (int k = 0; k < DD; ++k) {
        float4 e = E4[(size_t)k * (NN / 4) + tid];
#pragma unroll
        for (int r = 0; r < 4; ++r) {
            float xv = xr[r][k];
            acc[r].x += xv * e.x; acc[r].y += xv * e.y;
            acc[r].z += xv * e.z; acc[r].w += xv * e.w;
        }
    }
    float s[4], ss[4];
#pragma unroll
    for (int r = 0; r < 4; ++r) {
        s[r]  = acc[r].x + acc[r].y + acc[r].z + acc[r].w;
        ss[r] = acc[r].x*acc[r].x + acc[r].y*acc[r].y + acc[r].z*acc[r].z + acc[r].w*acc[r].w;
    }
#pragma unroll
    for (int d = 1; d < 64; d <<= 1) {
#pragma unroll
        for (int r = 0; r < 4; ++r) {
            s[r]  += __shfl_xor(s[r], d, 64);
            ss[r] += __shfl_xor(ss[r], d, 64);
        }
    }
    if (lane == 0) {
#pragma unroll
        for (int r = 0; r < 4; ++r) { redS[w][r] = s[r]; redSS[w][r] = ss[r]; }
    }
    __syncthreads();
#pragma unroll
    for (int r = 0; r < 4; ++r) {
        s[r]  = redS[0][r] + redS[1][r] + redS[2][r] + redS[3][r];
        ss[r] = redSS[0][r] + redSS[1][r] + redSS[2][r] + redSS[3][r];
    }

#pragma unroll
    for (int r = 0; r < 4; ++r) {
        const float mu  = s[r] * (1.0f / NN);
        const float var = ss[r] * (1.0f / NN) - mu * mu;
        const float inv = rsqrtf(var + 1e-5f);
        float4 o;
        o.x = fmaxf(0.f, (acc[r].x - mu) * inv);
        o.y = fmaxf(0.f, (acc[r].y - mu) * inv);
        o.z = fmaxf(0.f, (acc[r].z - mu) * inv);
        o.w = fmaxf(0.f, (acc[r].w - mu) * inv);
        const int bt = (r & 1) ? bt1 : bt0;
        float* dst = nullptr;
        if (r < 2) dst = ws + XN_OFF + (size_t)bt * NN;             // xn[bt]
        else if ((bt & 31) > 0) dst = ws + TN_OFF + (size_t)(bt - 1) * NN; // tn_next[bt-1]
        if (dst) ((float4*)dst)[tid] = o;
    }
}

// ------------- kernel 2: persistent per-batch chain, flag-embedded sync -------------
__device__ __forceinline__ float poll_slot(const unsigned long long* p, unsigned seq) {
    unsigned long long u;
    int guard = 0;
    do {
        u = __hip_atomic_load(p, __ATOMIC_RELAXED, __HIP_MEMORY_SCOPE_AGENT);
        if (++guard > (1 << 26)) break;   // bailout: fail visibly, don't hang
    } while ((unsigned)u != seq);
    return __uint_as_float((unsigned)(u >> 32));
}

__global__ __launch_bounds__(512, 2) void chain_kernel(
    const float* __restrict__ Dy, float* __restrict__ ws)
{
    __shared__ float x_lds[NN];
    __shared__ float p_lds[NN];
    __shared__ float r_lds[64];
    __shared__ float tn_lds[64];

    const int blk  = blockIdx.x;     // 64 blocks
    const int b    = blk >> 4;       // batch
    const int wg   = blk & 15;       // 16 WGs per batch
    const int base = wg * 64;        // first owned column
    const int tid  = threadIdx.x;
    const int lane = tid & 63;
    const int w    = tid >> 6;       // wave 0..7
    const int g    = lane & 7;       // row-group: rows [g*128, g*128+128)
    const int ci   = lane >> 3;      // col within wave: 0..7
    const int cg   = base + 8 * w + ci;  // this lane's global column
    const int rb   = g * 128;

    const float* xn = ws + XN_OFF + (size_t)b * TT * NN;
    const float* tn = ws + TN_OFF + (size_t)b * TT * NN;
    unsigned long long* pb64 = (unsigned long long*)(ws + PB_OFF);
    float* yw = ws + YW_OFF;

    // G: this lane holds 128 rows x 1 col. G[4q+k] = G[rb + 4*(q^g) + k][cg]
    // (XOR swizzle so the 8 row-groups' float4 LDS reads hit 8 distinct bank quads)
    float G[128];
#pragma unroll
    for (int q = 0; q < 32; ++q) {
        const int row4 = rb + 4 * (q ^ g);
#pragma unroll
        for (int k = 0; k < 4; ++k)
            G[4*q + k] = (row4 + k == cg) ? 0.01f : 0.0f;
    }

    // matvec: returns p_next[cg] = sum_n v[n] * G[n][cg] (all lanes get the value)
    auto matvec = [&](const float* v_lds) -> float {
        const float4* v4 = (const float4*)v_lds;
        const int vb = g * 32;
        float a0 = 0.f, a1 = 0.f, a2 = 0.f, a3 = 0.f;
#pragma unroll
        for (int q = 0; q < 32; q += 4) {
            float4 x0 = v4[vb + ((q + 0) ^ g)];
            float4 x1 = v4[vb + ((q + 1) ^ g)];
            float4 x2 = v4[vb + ((q + 2) ^ g)];
            float4 x3 = v4[vb + ((q + 3) ^ g)];
            a0 += x0.x*G[4*q+ 0] + x0.y*G[4*q+ 1] + x0.z*G[4*q+ 2] + x0.w*G[4*q+ 3];
            a1 += x1.x*G[4*q+ 4] + x1.y*G[4*q+ 5] + x1.z*G[4*q+ 6] + x1.w*G[4*q+ 7];
            a2 += x2.x*G[4*q+ 8] + x2.y*G[4*q+ 9] + x2.z*G[4*q+10] + x2.w*G[4*q+11];
            a3 += x3.x*G[4*q+12] + x3.y*G[4*q+13] + x3.z*G[4*q+14] + x3.w*G[4*q+15];
        }
        float acc = (a0 + a1) + (a2 + a3);
        acc += __shfl_xor(acc, 1, 64);  // reduce across the 8 row-groups
        acc += __shfl_xor(acc, 2, 64);
        acc += __shfl_xor(acc, 4, 64);
        return acc;
    };

    for (int t = 0; t < TT; ++t) {
        const int bt = b * TT + t;
        __syncthreads();  // protect x_lds/tn_lds vs previous iteration's readers
        x_lds[tid]       = xn[(size_t)t * NN + tid];
        x_lds[tid + 512] = xn[(size_t)t * NN + tid + 512];
        if (t < TT - 1 && tid < 64) tn_lds[tid] = tn[(size_t)t * NN + base + tid];
        __syncthreads();

        // ---- phase A: p1 = xn^T G ----
        float v1 = matvec(x_lds);
        {
            const unsigned seq = (unsigned)(bt * 2 + 1);
            unsigned long long* slot = pb64 + (size_t)(bt * 2 + 0) * NN;
            if (g == 0) {
                unsigned long long u = ((unsigned long long)__float_as_uint(v1) << 32) | seq;
                __hip_atomic_store(slot + cg, u, __ATOMIC_RELAXED, __HIP_MEMORY_SCOPE_AGENT);
            }
            // gather p1 (all 1024 entries) via direct data-poll
            p_lds[tid]       = poll_slot(slot + tid, seq);
            p_lds[tid + 512] = poll_slot(slot + tid + 512, seq);
        }
        __syncthreads();

        // ---- phase B: p2 = p1^T G ----
        float v2 = matvec(p_lds);
        __syncthreads();  // everyone done reading p_lds before overwrite
        {
            const unsigned seq = (unsigned)(bt * 2 + 2);
            unsigned long long* slot = pb64 + (size_t)(bt * 2 + 1) * NN;
            if (g == 0) {
                unsigned long long u = ((unsigned long long)__float_as_uint(v2) << 32) | seq;
                __hip_atomic_store(slot + cg, u, __ATOMIC_RELAXED, __HIP_MEMORY_SCOPE_AGENT);
            }
            p_lds[tid]       = poll_slot(slot + tid, seq);
            p_lds[tid + 512] = poll_slot(slot + tid + 512, seq);
        }
        __syncthreads();

        // ---- phase C: p3 = p2^T G (consumed locally) ----
        float v3 = matvec(p_lds);

        float r = fmaxf(v1, fmaxf(v2, v3));
        if (g == 0) r_lds[8 * w + ci] = r;
        __syncthreads();

        // ---- y partial: y[d] += sum over owned cols r[col]*Dy[col][d] ----
        {
            const int d = tid & 255;
            const int h = tid >> 8;  // 0/1: halves of the 64 owned columns
            float acc = 0.f;
#pragma unroll
            for (int j = 0; j < 32; ++j) {
                const int cl = h * 32 + j;
                acc += r_lds[cl] * Dy[(size_t)(base + cl) * DD + d];
            }
            atomicAdd(&yw[(size_t)bt * DD + d], acc);
        }

        // ---- G update: G = max(G, 0.5*xn*tn_next^T), skip last step ----
        if (t < TT - 1) {
            const float tc = 0.5f * tn_lds[8 * w + ci];
            const float4* x4 = (const float4*)x_lds;
#pragma unroll
            for (int q = 0; q < 32; ++q) {
                float4 xv = x4[g * 32 + (q ^ g)];
                G[4*q+0] = fmaxf(G[4*q+0], xv.x * tc);
                G[4*q+1] = fmaxf(G[4*q+1], xv.y * tc);
                G[4*q+2] = fmaxf(G[4*q+2], xv.z * tc);
                G[4*q+3] = fmaxf(G[4*q+3], xv.w * tc);
            }
        }
    }
}

// ------------- kernel 3: final relu -------------
__global__ __launch_bounds__(256) void relu_out_kernel(
    const float* __restrict__ yw, float* __restrict__ out, int n)
{
    int i = blockIdx.x * blockDim.x + threadIdx.x;
    if (i < n) out[i] = fmaxf(yw[i], 0.0f);
}

extern "C" void kernel_launch(void* const* d_in, const int* in_sizes, int n_in,
                              void* d_out, int out_size, void* d_ws, size_t ws_size,
                              hipStream_t stream) {
    const float* x_seq   = (const float*)d_in[0];
    const float* targets = (const float*)d_in[1];
    const float* E       = (const float*)d_in[2];
    const float* Dy      = (const float*)d_in[3];
    float* out = (float*)d_out;
    float* ws  = (float*)d_ws;

    // zero pb64 (flag slots; stale/poison != seq) + y accumulator (contiguous)
    hipMemsetAsync(ws + PB_OFF, 0,
                   (size_t)(4 * BB * TT * NN + BB * TT * DD) * sizeof(float), stream);

    // 64 blocks: each handles 2 bt's x {x_seq, targets}
    precompute_kernel<<<BB * TT / 2, 256, 0, stream>>>(x_seq, targets, E, ws);
    chain_kernel<<<BB * 16, 512, 0, stream>>>(Dy, ws);
    relu_out_kernel<<<(BB * TT * DD + 255) / 256, 256, 0, stream>>>(ws + YW_OFF, out, BB * TT * DD);
}